// Round 9
// baseline (517.372 us; speedup 1.0000x reference)
//
#include <hip/hip_runtime.h>
#include <hip/hip_bf16.h>
#include <stdint.h>

// MiniMax lightning attention, MI355X bf16-MFMA implementation.
// B=2 N=4096 H=2048 NH=16 HD=128 BLK=256 NB=16.
// R15 (on R14's proven 256x256 single-sync GEMM, untouched inner loop):
//  (a) gate GEMM merged into QKV GEMM: wqkvb+wgateb are adjacent 256-aligned
//      allocations = one [8192][2048] weight matrix; N=8192, grid 1024;
//      epilogue routes colb>=6144 -> sigmoid -> gate_s. Aliases: gate_s=ctbuf
//      (exact 32MiB fit), CT=(float*)d_out (dead interval disjoint).
//  (b) pass_attn writes bf16 scratch (was f32): -67MB HBM round trip;
//      rmsnorm reads bf16. o is rounded to bf16 after norm anyway.
//  (c) pass_ct decay via recurrence: 8 expf + 56 muls (was 64 expf);
//      f<=1 monotone, no overflow; underflowed terms are ~e^-98, negligible.
// Proven pieces kept verbatim: slot^(row&7) swizzle, single-sync K-loop,
// direct-transposed kT/vT epilogue, balanced-triangle pass_attn w/ Q-hoist,
// element-parallel scan_kv, fused cvt4.

typedef __bf16 bf16_t;
typedef __bf16 bf16x8 __attribute__((ext_vector_type(8)));
typedef __bf16 bf16x4 __attribute__((ext_vector_type(4)));
typedef float  f32x4  __attribute__((ext_vector_type(4)));

#define AS1C(p) ((const __attribute__((address_space(1))) void*)(p))
#define AS3(p)  ((__attribute__((address_space(3))) void*)(p))

// ---------------- fused f32 -> bf16 convert (4 tensors, one launch) ----------------
__global__ __launch_bounds__(256)
void cvt4_kernel(const float* __restrict__ s0, bf16_t* __restrict__ d0, int n0,
                 const float* __restrict__ s1, bf16_t* __restrict__ d1, int n1,
                 const float* __restrict__ s2, bf16_t* __restrict__ d2, int n2,
                 const float* __restrict__ s3, bf16_t* __restrict__ d3, int n3) {
    const int total = n0 + n1 + n2 + n3;
    const int stride = gridDim.x * blockDim.x;
    for (int i = blockIdx.x * blockDim.x + threadIdx.x; i < total; i += stride) {
        const float* s; bf16_t* d; int j = i;
        if (j < n0) { s = s0; d = d0; }
        else {
            j -= n0;
            if (j < n1) { s = s1; d = d1; }
            else {
                j -= n1;
                if (j < n2) { s = s2; d = d2; }
                else { j -= n2; s = s3; d = d3; }
            }
        }
        float4 v = ((const float4*)s)[j];
        bf16x4 o;
        o[0] = (bf16_t)v.x; o[1] = (bf16_t)v.y; o[2] = (bf16_t)v.z; o[3] = (bf16_t)v.w;
        ((bf16x4*)d)[j] = o;
    }
}

// ---------------- single-sync bf16 GEMM, C = A @ B^T (A:[M][K], B:[N][K]) ----------------
// BM=BN=256 BK=64; 512 threads = 8 waves (2M x 4N); per-wave 128x64 output.
// LDS per dbuf (64KB): A [256][128B] @0, B [256][128B] @32768; slot^(row&7) swizzle.
// Per K-tile: {vmcnt(0) [lands stage(t), issued one full tile earlier]; barrier;
//   reads m0-3 + B; stage(t+1) 8 loads; 32 MFMA; reads m4-7; 32 MFMA}.
// EPI 0: combined epilogue — colb<6144: silu -> scatter q/kb + direct-transposed
//        kT/vT; colb>=6144: sigmoid -> gate_s (outb) row-major [8192][2048].
// EPI 2: f32 out
template <int EPI>
__global__ __launch_bounds__(512)
void gemm6(const bf16_t* __restrict__ A, const bf16_t* __restrict__ Bm,
           int M, int N, int K,
           float* __restrict__ outf, bf16_t* __restrict__ outb,
           bf16_t* __restrict__ qb, bf16_t* __restrict__ kb,
           bf16_t* __restrict__ kT, bf16_t* __restrict__ vT,
           const float* __restrict__ slopes) {
    __shared__ char lds[2][65536];
    const int tid = threadIdx.x, w = tid >> 6, lane = tid & 63;
    const int l15 = lane & 15, lq = lane >> 4;
    const int wr = w >> 2, wc = w & 3;

    // XCD-aware bijective swizzle of the flattened grid (gridDim.x % 8 == 0)
    const int nwg = gridDim.x;
    const int cpx = nwg >> 3;
    const int id = blockIdx.x;
    const int sw = (id & 7) * cpx + (id >> 3);
    const int gx = N >> 8;
    const int tm = (sw / gx) << 8;
    const int tn = (sw % gx) << 8;
    const int nt = K >> 6;

    // stage one 64-row slice (j) of A or B for K-tile t1: 1 x 16B load per thread.
    // LDS dest linear (chunk c at byte c*16); global source pre-swizzled with the
    // same involution the reads use: slot ^ (row&7).
    auto stageA1 = [&](char* dst, int t1, int j) {
        const bf16_t* base = A + (size_t)tm * K + t1 * 64;
        const int c = tid + j * 512;           // rows 64j..64j+63
        const int r = c >> 3, sl = c & 7;
        __builtin_amdgcn_global_load_lds(
            AS1C(base + (size_t)r * K + ((sl ^ (r & 7)) << 3)),
            AS3(dst + c * 16), 16, 0, 0);
    };
    auto stageB1 = [&](char* dst, int t1, int j) {
        const bf16_t* base = Bm + (size_t)tn * K + t1 * 64;
        const int c = tid + j * 512;
        const int r = c >> 3, sl = c & 7;
        __builtin_amdgcn_global_load_lds(
            AS1C(base + (size_t)r * K + ((sl ^ (r & 7)) << 3)),
            AS3(dst + 32768 + c * 16), 16, 0, 0);
    };

    f32x4 acc[8][4] = {};

    // prologue: stage tile 0 (8 loads)
    {
        char* d0 = &lds[0][0];
        stageA1(d0, 0, 0); stageA1(d0, 0, 1); stageA1(d0, 0, 2); stageA1(d0, 0, 3);
        stageB1(d0, 0, 0); stageB1(d0, 0, 1); stageB1(d0, 0, 2); stageB1(d0, 0, 3);
    }

    for (int t = 0; t < nt; ++t) {
        const char* cur = &lds[t & 1][0];
        char* nxt = &lds[1 - (t & 1)][0];
        const bool pre = (t + 1 < nt);

        // single sync point: stage(t) landed (issued one full tile ago)
        asm volatile("s_waitcnt vmcnt(0)" ::: "memory");
        __builtin_amdgcn_s_barrier();
        __builtin_amdgcn_sched_barrier(0);

        bf16x8 bfr[4][2], af[4][2];
#pragma unroll
        for (int n = 0; n < 4; ++n)
#pragma unroll
            for (int kk = 0; kk < 2; ++kk) {
                const int row = wc * 64 + n * 16 + l15;
                bfr[n][kk] = *(const bf16x8*)(cur + 32768 + row * 128 + ((((kk << 2) | lq) ^ (row & 7)) << 4));
            }
#pragma unroll
        for (int m = 0; m < 4; ++m)
#pragma unroll
            for (int kk = 0; kk < 2; ++kk) {
                const int row = wr * 128 + m * 16 + l15;
                af[m][kk] = *(const bf16x8*)(cur + row * 128 + ((((kk << 2) | lq) ^ (row & 7)) << 4));
            }
        if (pre) {                                          // stage(t+1): 8 loads, fly all tile
            stageA1(nxt, t + 1, 0); stageA1(nxt, t + 1, 1);
            stageA1(nxt, t + 1, 2); stageA1(nxt, t + 1, 3);
            stageB1(nxt, t + 1, 0); stageB1(nxt, t + 1, 1);
            stageB1(nxt, t + 1, 2); stageB1(nxt, t + 1, 3);
        }
        __builtin_amdgcn_s_setprio(1);
#pragma unroll
        for (int m = 0; m < 4; ++m)
#pragma unroll
            for (int n = 0; n < 4; ++n)
#pragma unroll
                for (int kk = 0; kk < 2; ++kk)
                    acc[m][n] = __builtin_amdgcn_mfma_f32_16x16x32_bf16(af[m][kk], bfr[n][kk], acc[m][n], 0, 0, 0);
        __builtin_amdgcn_s_setprio(0);

        // second half: rows 64-127 of the wave's panel; same buffer, no sync needed
#pragma unroll
        for (int m = 0; m < 4; ++m)
#pragma unroll
            for (int kk = 0; kk < 2; ++kk) {
                const int row = wr * 128 + 64 + m * 16 + l15;
                af[m][kk] = *(const bf16x8*)(cur + row * 128 + ((((kk << 2) | lq) ^ (row & 7)) << 4));
            }
        __builtin_amdgcn_s_setprio(1);
#pragma unroll
        for (int m = 0; m < 4; ++m)
#pragma unroll
            for (int n = 0; n < 4; ++n)
#pragma unroll
                for (int kk = 0; kk < 2; ++kk)
                    acc[4 + m][n] = __builtin_amdgcn_mfma_f32_16x16x32_bf16(af[m][kk], bfr[n][kk], acc[4 + m][n], 0, 0, 0);
        __builtin_amdgcn_s_setprio(0);
    }

    // epilogue. C frag layout: row = lq*4 + r, col = l15
#pragma unroll
    for (int m = 0; m < 8; ++m) {
#pragma unroll
        for (int n = 0; n < 4; ++n) {
            const int colb = tn + wc * 64 + n * 16;   // wave-uniform 16-col group
            if (EPI == 2) {
#pragma unroll
                for (int r = 0; r < 4; ++r) {
                    const int row = tm + wr * 128 + m * 16 + lq * 4 + r;
                    outf[(size_t)row * N + colb + l15] = acc[m][n][r];
                }
            } else {
                if (colb >= 6144) {
                    // gate region: sigmoid -> gate_s (outb), row-major [8192][2048]
#pragma unroll
                    for (int r = 0; r < 4; ++r) {
                        const int row = tm + wr * 128 + m * 16 + lq * 4 + r;
                        const float v = acc[m][n][r];
                        outb[(size_t)row * 2048 + (colb - 6144) + l15] = (bf16_t)(1.f / (1.f + __expf(-v)));
                    }
                } else {
                    const int head = colb / 384;
                    const int jj = colb % 384;
                    const int row0 = tm + wr * 128 + m * 16 + lq * 4;  // 4-aligned
                    const int bidx = row0 >> 12;
                    const int nn0 = row0 & 4095;
                    const size_t bh = (size_t)(bidx * 16 + head);
                    float sv[4];
#pragma unroll
                    for (int r = 0; r < 4; ++r) {
                        const float v = acc[m][n][r];
                        sv[r] = v / (1.f + __expf(-v));    // silu
                    }
                    if (jj < 128) {
                        bf16_t* qp = qb + (bh * 4096 + nn0) * 128 + jj + l15;
#pragma unroll
                        for (int r = 0; r < 4; ++r) qp[(size_t)r * 128] = (bf16_t)sv[r];
                    } else if (jj < 256) {
                        // row-major kb (for QK^T) + direct-transposed kT (for pass_ct)
                        bf16_t* kp = kb + (bh * 4096 + nn0) * 128 + (jj - 128) + l15;
#pragma unroll
                        for (int r = 0; r < 4; ++r) kp[(size_t)r * 128] = (bf16_t)sv[r];
                        bf16x4 pk;
#pragma unroll
                        for (int r = 0; r < 4; ++r) pk[r] = (bf16_t)sv[r];
                        *(bf16x4*)(kT + bh * 524288 + (size_t)(jj - 128 + l15) * 4096 + nn0) = pk;
                    } else {
                        // v only needed feature-major: direct-transposed vT, no vb
                        bf16x4 pv;
#pragma unroll
                        for (int r = 0; r < 4; ++r) pv[r] = (bf16_t)sv[r];
                        *(bf16x4*)(vT + bh * 524288 + (size_t)(jj - 256 + l15) * 4096 + nn0) = pv;
                    }
                }
            }
        }
    }
}

// ---------------- per-block KV contribution with on-the-fly k-decay ----------------
// CT[e][d] = sum_m vT[e][m] * (kT[d][m] * exp(-s*(255-m)))
// decay via recurrence: f(t+1) = f(t) * e^s (f <= 1, monotone increasing)
__global__ __launch_bounds__(256)
void pass_ct(const bf16_t* __restrict__ vT, const bf16_t* __restrict__ kT,
             float* __restrict__ CT, const float* __restrict__ slopes) {
    const int idx = blockIdx.x, bh = idx >> 4, j = idx & 15;
    const float s = slopes[bh & 15];
    const float r_ = __expf(s);
    const int tid = threadIdx.x, w = tid >> 6, lane = tid & 63;
    const int l15 = lane & 15, lq = lane >> 4;
    const int we = (w & 1) * 64, wd = (w >> 1) * 64;
    const bf16_t* va = vT + (size_t)bh * 524288 + j * 256;
    const bf16_t* ka = kT + (size_t)bh * 524288 + j * 256;
    f32x4 acc[4][4] = {};
#pragma unroll
    for (int kk = 0; kk < 8; ++kk) {
        float fdec[8];
        fdec[0] = __expf(-s * (float)(255 - (kk * 32 + lq * 8)));
#pragma unroll
        for (int t = 1; t < 8; ++t) fdec[t] = fdec[t - 1] * r_;
        bf16x8 af[4], bfv[4];
#pragma unroll
        for (int et = 0; et < 4; ++et)
            af[et] = *(const bf16x8*)(va + (size_t)(we + et * 16 + l15) * 4096 + kk * 32 + lq * 8);
#pragma unroll
        for (int dt = 0; dt < 4; ++dt) {
            bf16x8 raw = *(const bf16x8*)(ka + (size_t)(wd + dt * 16 + l15) * 4096 + kk * 32 + lq * 8);
#pragma unroll
            for (int t = 0; t < 8; ++t) bfv[dt][t] = (bf16_t)((float)raw[t] * fdec[t]);
        }
#pragma unroll
        for (int et = 0; et < 4; ++et)
#pragma unroll
            for (int dt = 0; dt < 4; ++dt)
                acc[et][dt] = __builtin_amdgcn_mfma_f32_16x16x32_bf16(af[et], bfv[dt], acc[et][dt], 0, 0, 0);
    }
    float* out = CT + (size_t)idx * 16384;
#pragma unroll
    for (int et = 0; et < 4; ++et)
#pragma unroll
        for (int dt = 0; dt < 4; ++dt)
#pragma unroll
            for (int r = 0; r < 4; ++r)
                out[(size_t)(we + et * 16 + lq * 4 + r) * 128 + wd + dt * 16 + l15] = acc[et][dt][r];
}

// ---------------- sequential scan: states[j] = kv state before block j (bf16, [e][d]) ----------------
// one thread per (bh, elem): 32*16384 = 524288 scans; fully coalesced.
__global__ __launch_bounds__(256)
void scan_kv(const float* __restrict__ CT, bf16_t* __restrict__ states,
             const float* __restrict__ slopes) {
    const int gid = blockIdx.x * 256 + threadIdx.x;
    const int bh = gid >> 14, elem = gid & 16383;
    const float s = slopes[bh & 15];
    const float bd = __expf(-s * 256.f);
    const float* c = CT + (size_t)bh * 16 * 16384 + elem;
    bf16_t* st = states + (size_t)bh * 16 * 16384 + elem;
    float kv = 0.f;
#pragma unroll
    for (int j = 0; j < 16; ++j) {
        st[(size_t)j * 16384] = (bf16_t)kv;
        kv = bd * kv + c[(size_t)j * 16384];
    }
}

// ---------------- per-block output: o = (q*qdecay) @ stateT^T + (q@k^T . decay) @ v ----------------
// Balanced triangle: wave w owns 16-row groups {w, 15-w}; every wave does
// exactly 9 half-iters. Q hoisted; output written as bf16 (rmsnorm rounds
// to bf16 anyway).
__global__ __launch_bounds__(512)
void pass_attn(const bf16_t* __restrict__ qb, const bf16_t* __restrict__ kb,
               const bf16_t* __restrict__ vT, const bf16_t* __restrict__ states,
               const float* __restrict__ slopes, bf16_t* __restrict__ outattn) {
    __shared__ bf16_t scratch[8][16][40];
    const int idx = blockIdx.x, bh = idx >> 4, j = idx & 15;
    const int b = bh >> 4, h = bh & 15;
    const int tid = threadIdx.x, w = tid >> 6, lane = tid & 63;
    const int l15 = lane & 15, lq = lane >> 4;
    const float s = slopes[h];
    f32x4 o[2][8] = {};    // [group][et]
    float rowf[4];         // exp(-s * local_row) ; local row within 16-group
#pragma unroll
    for (int r = 0; r < 4; ++r) rowf[r] = __expf(-s * (float)(lq * 4 + r));

    const size_t qrow = (size_t)bh * 4096 + j * 256;
    const bf16_t* qbase = qb + qrow * 128;
    const bf16_t* kbp = kb + qrow * 128;
    const bf16_t* vtp = vT + (size_t)bh * 524288 + (size_t)j * 256;

#pragma unroll
    for (int gi = 0; gi < 2; ++gi) {
        const int gg = gi ? (15 - w) : w;          // 16-row group index
        const bf16_t* qg = qbase + (size_t)(gg * 16) * 128;
        // hoist the wave's q fragments (loop-invariant across nc)
        bf16x8 qf[4];
#pragma unroll
        for (int kq = 0; kq < 4; ++kq)
            qf[kq] = *(const bf16x8*)(qg + (size_t)l15 * 128 + kq * 32 + lq * 8);
        const int ncmax = gg >> 1;                 // 32-col chunks needed
        for (int nc = 0; nc <= ncmax; ++nc) {
            f32x4 sacc[2] = {};
#pragma unroll
            for (int kq = 0; kq < 4; ++kq) {
                bf16x8 b0 = *(const bf16x8*)(kbp + (size_t)(nc * 32 + l15) * 128 + kq * 32 + lq * 8);
                bf16x8 b1 = *(const bf16x8*)(kbp + (size_t)(nc * 32 + 16 + l15) * 128 + kq * 32 + lq * 8);
                sacc[0] = __builtin_amdgcn_mfma_f32_16x16x32_bf16(qf[kq], b0, sacc[0], 0, 0, 0);
                sacc[1] = __builtin_amdgcn_mfma_f32_16x16x32_bf16(qf[kq], b1, sacc[1], 0, 0, 0);
            }
#pragma unroll
            for (int nt = 0; nt < 2; ++nt) {
                const float colf = __expf(s * (float)(nc * 32 + nt * 16 + l15 - gg * 16));
#pragma unroll
                for (int r = 0; r < 4; ++r) {
                    const int mloc = lq * 4 + r;                // local row in group
                    const int nglob = nc * 32 + nt * 16 + l15;  // global col
                    const float f = (gg * 16 + mloc >= nglob) ? rowf[r] * colf : 0.f;
                    scratch[w][mloc][nt * 16 + l15] = (bf16_t)(sacc[nt][r] * f);
                }
            }
            bf16x8 sa = *(const bf16x8*)&scratch[w][l15][lq * 8];
            __builtin_amdgcn_s_setprio(1);
#pragma unroll
            for (int et = 0; et < 8; ++et) {
                bf16x8 bv = *(const bf16x8*)(vtp + (size_t)(et * 16 + l15) * 4096 + nc * 32 + lq * 8);
                o[gi][et] = __builtin_amdgcn_mfma_f32_16x16x32_bf16(sa, bv, o[gi][et], 0, 0, 0);
            }
            __builtin_amdgcn_s_setprio(0);
        }
    }

    // inter-block part: o += (q * exp(-s*(row+1))) @ state
    float rq[2];
    rq[0] = __expf(-s * (float)(w * 16 + l15 + 1));
    rq[1] = __expf(-s * (float)((15 - w) * 16 + l15 + 1));
    const bf16_t* st = states + (size_t)idx * 16384;
#pragma unroll
    for (int kq = 0; kq < 4; ++kq) {
        bf16x8 aq[2];
#pragma unroll
        for (int gi = 0; gi < 2; ++gi) {
            const int gg = gi ? (15 - w) : w;
            bf16x8 raw = *(const bf16x8*)(qbase + (size_t)(gg * 16 + l15) * 128 + kq * 32 + lq * 8);
#pragma unroll
            for (int t = 0; t < 8; ++t) aq[gi][t] = (bf16_t)((float)raw[t] * rq[gi]);
        }
        __builtin_amdgcn_s_setprio(1);
#pragma unroll
        for (int et = 0; et < 8; ++et) {
            bf16x8 bs = *(const bf16x8*)(st + (size_t)(et * 16 + l15) * 128 + kq * 32 + lq * 8);
            o[0][et] = __builtin_amdgcn_mfma_f32_16x16x32_bf16(aq[0], bs, o[0][et], 0, 0, 0);
            o[1][et] = __builtin_amdgcn_mfma_f32_16x16x32_bf16(aq[1], bs, o[1][et], 0, 0, 0);
        }
        __builtin_amdgcn_s_setprio(0);
    }

    bf16_t* opb = outattn + ((size_t)b * 4096 + j * 256) * 2048 + h * 128;
#pragma unroll
    for (int gi = 0; gi < 2; ++gi) {
        const int gg = gi ? (15 - w) : w;
#pragma unroll
        for (int et = 0; et < 8; ++et)
#pragma unroll
            for (int r = 0; r < 4; ++r)
                opb[(size_t)(gg * 16 + lq * 4 + r) * 2048 + et * 16 + l15] = (bf16_t)o[gi][et][r];
    }
}

// ---------------- RMSNorm + sigmoid-gate fuse -> bf16 ----------------
__global__ __launch_bounds__(256)
void rmsnorm_gate(const bf16_t* __restrict__ attn, const bf16_t* __restrict__ gate_s,
                  const float* __restrict__ norm_w, bf16_t* __restrict__ gout) {
    const int row = blockIdx.x, tid = threadIdx.x;
    const bf16x8 a8 = *(const bf16x8*)(attn + (size_t)row * 2048 + tid * 8);
    float av[8];
#pragma unroll
    for (int i = 0; i < 8; ++i) av[i] = (float)a8[i];
    float ss = 0.f;
#pragma unroll
    for (int i = 0; i < 8; ++i) ss += av[i] * av[i];
#pragma unroll
    for (int off = 32; off; off >>= 1) ss += __shfl_xor(ss, off);
    __shared__ float red[4];
    if ((tid & 63) == 0) red[tid >> 6] = ss;
    __syncthreads();
    const float rr = rsqrtf((red[0] + red[1] + red[2] + red[3]) * (1.0f / 2048.f) + 1e-6f);
    const bf16x8 g = *(const bf16x8*)(gate_s + (size_t)row * 2048 + tid * 8);
    const float* nw = norm_w + tid * 8;
    bf16x8 res;
#pragma unroll
    for (int i = 0; i < 8; ++i) res[i] = (bf16_t)((float)g[i] * nw[i] * av[i] * rr);
    *(bf16x8*)(gout + (size_t)row * 2048 + tid * 8) = res;
}

// ---------------- launch ----------------
extern "C" void kernel_launch(void* const* d_in, const int* in_sizes, int n_in,
                              void* d_out, int out_size, void* d_ws, size_t ws_size,
                              hipStream_t stream) {
    (void)in_sizes; (void)n_in; (void)out_size;
    const float* x      = (const float*)d_in[0];
    const float* slopes = (const float*)d_in[1];
    const float* w_qkv  = (const float*)d_in[2];
    const float* w_gate = (const float*)d_in[3];
    const float* w_out  = (const float*)d_in[4];
    const float* norm_w = (const float*)d_in[5];
    float* out = (float*)d_out;
    char* ws = (char*)d_ws;

    size_t off = 0;
    auto alloc = [&](size_t bytes) { char* p = ws + off; off += (bytes + 255) & ~(size_t)255; return p; };
    bf16_t* xb     = (bf16_t*)alloc(8192ull * 2048 * 2);   // 33.6 MB
    bf16_t* wqkvb  = (bf16_t*)alloc(6144ull * 2048 * 2);   // 25.2 MB (25165824 B, 256-divisible)
    bf16_t* wgateb = (bf16_t*)alloc(2048ull * 2048 * 2);   //  8.4 MB — ADJACENT to wqkvb:
                                                           //  [wqkvb;wgateb] = one [8192][2048] matrix
    bf16_t* woutb  = (bf16_t*)alloc(2048ull * 2048 * 2);   //  8.4 MB
    bf16_t* qb     = (bf16_t*)alloc(33554432);             // [bh][4096][128]
    bf16_t* kb     = (bf16_t*)alloc(33554432);             // [bh][4096][128]
    char*   ctbuf  = alloc(33554432);                      // gate_s [8192][2048] bf16 (exact fit)
    bf16_t* vT     = (bf16_t*)alloc(33554432);             // [bh][128][4096]
    bf16_t* kT     = (bf16_t*)alloc(33554432);             // [bh][128][4096]
    if (ws_size < off) return;   // clean fail instead of OOB fault
    // aliases (producer runs strictly after last consumer of the aliased buffer):
    bf16_t* gate_s = (bf16_t*)ctbuf;   // written by combined gemm (step 2), read step 6
    float*  CT     = (float*)out;      // pass_ct out (32MB, steps 3-4); d_out f32 unused until step 5
    bf16_t* attn_s = (bf16_t*)out;     // pass_attn bf16 scratch (steps 5-6); clobbers dead CT
    bf16_t* states = (bf16_t*)wqkvb;   // scan output (16.8 MB) — weights dead after step 2
    bf16_t* gout   = qb;               // rmsnorm output — qb dead after pass_attn

    // 1. fused bf16 conversions (one launch)
    cvt4_kernel<<<2048, 256, 0, stream>>>(
        x,      xb,     8192 * 2048 / 4,
        w_qkv,  wqkvb,  6144 * 2048 / 4,
        w_gate, wgateb, 2048 * 2048 / 4,
        w_out,  woutb,  2048 * 2048 / 4);
    // 2. combined QKV+gate projection (N=8192 over [wqkvb;wgateb]); silu scatter
    //    q/kb/kT/vT for cols<6144, sigmoid->gate_s for cols>=6144. grid 32*32=1024.
    gemm6<0><<<1024, 512, 0, stream>>>(xb, wqkvb, 8192, 8192, 2048,
        nullptr, gate_s, qb, kb, kT, vT, slopes);
    // 3. per-block KV contributions (k-decay recurrence); CT -> d_out scratch
    pass_ct<<<512, 256, 0, stream>>>(vT, kT, CT, slopes);
    // 4. sequential KV scan (reads CT from d_out; writes states over dead weights)
    scan_kv<<<2048, 256, 0, stream>>>(CT, states, slopes);
    // 5. attention block outputs -> bf16 scratch in d_out (clobbers dead CT)
    pass_attn<<<512, 512, 0, stream>>>(qb, kb, vT, states, slopes, attn_s);
    // 6. RMSNorm * norm_w * sigmoid(gate) -> bf16 (writes over qb — dead)
    rmsnorm_gate<<<8192, 256, 0, stream>>>(attn_s, gate_s, norm_w, gout);
    // 7. output projection -> d_out f32 (overwrites bf16 scratch after its last read)
    gemm6<2><<<256, 512, 0, stream>>>(gout, woutb, 8192, 2048, 2048,
        out, nullptr, nullptr, nullptr, nullptr, nullptr, nullptr);
}

// Round 10
// 491.660 us; speedup vs baseline: 1.0523x; 1.0523x over previous
//
#include <hip/hip_runtime.h>
#include <hip/hip_bf16.h>
#include <stdint.h>

// MiniMax lightning attention, MI355X bf16-MFMA implementation.
// B=2 N=4096 H=2048 NH=16 HD=128 BLK=256 NB=16.
// R16: R14 pipeline restored (split GEMMs: R15's merged N=8192 GEMM lost
// A-panel L2 reuse, FETCH 427->541MB, +6us; reverted). KEPT from R15:
//  (a) pass_attn writes bf16 scratch, rmsnorm reads bf16 (-67MB HBM
//      round trip; absmax validated unchanged in R15);
//  (b) pass_ct decay recurrence: 8 expf + 56 muls (was 64 expf).
// Proven pieces verbatim: 256x256 single-sync GEMM w/ slot^(row&7)
// swizzle, direct-transposed kT/vT epilogue, balanced-triangle pass_attn
// with Q-hoist + setprio, element-parallel scan_kv, fused cvt4.

typedef __bf16 bf16_t;
typedef __bf16 bf16x8 __attribute__((ext_vector_type(8)));
typedef __bf16 bf16x4 __attribute__((ext_vector_type(4)));
typedef float  f32x4  __attribute__((ext_vector_type(4)));

#define AS1C(p) ((const __attribute__((address_space(1))) void*)(p))
#define AS3(p)  ((__attribute__((address_space(3))) void*)(p))

// ---------------- fused f32 -> bf16 convert (4 tensors, one launch) ----------------
__global__ __launch_bounds__(256)
void cvt4_kernel(const float* __restrict__ s0, bf16_t* __restrict__ d0, int n0,
                 const float* __restrict__ s1, bf16_t* __restrict__ d1, int n1,
                 const float* __restrict__ s2, bf16_t* __restrict__ d2, int n2,
                 const float* __restrict__ s3, bf16_t* __restrict__ d3, int n3) {
    const int total = n0 + n1 + n2 + n3;
    const int stride = gridDim.x * blockDim.x;
    for (int i = blockIdx.x * blockDim.x + threadIdx.x; i < total; i += stride) {
        const float* s; bf16_t* d; int j = i;
        if (j < n0) { s = s0; d = d0; }
        else {
            j -= n0;
            if (j < n1) { s = s1; d = d1; }
            else {
                j -= n1;
                if (j < n2) { s = s2; d = d2; }
                else { j -= n2; s = s3; d = d3; }
            }
        }
        float4 v = ((const float4*)s)[j];
        bf16x4 o;
        o[0] = (bf16_t)v.x; o[1] = (bf16_t)v.y; o[2] = (bf16_t)v.z; o[3] = (bf16_t)v.w;
        ((bf16x4*)d)[j] = o;
    }
}

// ---------------- single-sync bf16 GEMM, C = A @ B^T (A:[M][K], B:[N][K]) ----------------
// BM=BN=256 BK=64; 512 threads = 8 waves (2M x 4N); per-wave 128x64 output.
// LDS per dbuf (64KB): A [256][128B] @0, B [256][128B] @32768; slot^(row&7) swizzle.
// Per K-tile: {vmcnt(0) [lands stage(t), issued one full tile earlier]; barrier;
//   reads m0-3 + B; stage(t+1) 8 loads; 32 MFMA; reads m4-7; 32 MFMA}.
// EPI 0: silu -> scatter q/kb + DIRECT-TRANSPOSED kT/vT ; EPI 1: sigmoid -> bf16 ;
// EPI 2: f32 out
template <int EPI>
__global__ __launch_bounds__(512)
void gemm6(const bf16_t* __restrict__ A, const bf16_t* __restrict__ Bm,
           int M, int N, int K,
           float* __restrict__ outf, bf16_t* __restrict__ outb,
           bf16_t* __restrict__ qb, bf16_t* __restrict__ kb,
           bf16_t* __restrict__ kT, bf16_t* __restrict__ vT,
           const float* __restrict__ slopes) {
    __shared__ char lds[2][65536];
    const int tid = threadIdx.x, w = tid >> 6, lane = tid & 63;
    const int l15 = lane & 15, lq = lane >> 4;
    const int wr = w >> 2, wc = w & 3;

    // XCD-aware bijective swizzle of the flattened grid (gridDim.x % 8 == 0)
    const int nwg = gridDim.x;
    const int cpx = nwg >> 3;
    const int id = blockIdx.x;
    const int sw = (id & 7) * cpx + (id >> 3);
    const int gx = N >> 8;
    const int tm = (sw / gx) << 8;
    const int tn = (sw % gx) << 8;
    const int nt = K >> 6;

    // stage one 64-row slice (j) of A or B for K-tile t1: 1 x 16B load per thread.
    // LDS dest linear (chunk c at byte c*16); global source pre-swizzled with the
    // same involution the reads use: slot ^ (row&7).
    auto stageA1 = [&](char* dst, int t1, int j) {
        const bf16_t* base = A + (size_t)tm * K + t1 * 64;
        const int c = tid + j * 512;           // rows 64j..64j+63
        const int r = c >> 3, sl = c & 7;
        __builtin_amdgcn_global_load_lds(
            AS1C(base + (size_t)r * K + ((sl ^ (r & 7)) << 3)),
            AS3(dst + c * 16), 16, 0, 0);
    };
    auto stageB1 = [&](char* dst, int t1, int j) {
        const bf16_t* base = Bm + (size_t)tn * K + t1 * 64;
        const int c = tid + j * 512;
        const int r = c >> 3, sl = c & 7;
        __builtin_amdgcn_global_load_lds(
            AS1C(base + (size_t)r * K + ((sl ^ (r & 7)) << 3)),
            AS3(dst + 32768 + c * 16), 16, 0, 0);
    };

    f32x4 acc[8][4] = {};

    // prologue: stage tile 0 (8 loads)
    {
        char* d0 = &lds[0][0];
        stageA1(d0, 0, 0); stageA1(d0, 0, 1); stageA1(d0, 0, 2); stageA1(d0, 0, 3);
        stageB1(d0, 0, 0); stageB1(d0, 0, 1); stageB1(d0, 0, 2); stageB1(d0, 0, 3);
    }

    for (int t = 0; t < nt; ++t) {
        const char* cur = &lds[t & 1][0];
        char* nxt = &lds[1 - (t & 1)][0];
        const bool pre = (t + 1 < nt);

        // single sync point: stage(t) landed (issued one full tile ago)
        asm volatile("s_waitcnt vmcnt(0)" ::: "memory");
        __builtin_amdgcn_s_barrier();
        __builtin_amdgcn_sched_barrier(0);

        bf16x8 bfr[4][2], af[4][2];
#pragma unroll
        for (int n = 0; n < 4; ++n)
#pragma unroll
            for (int kk = 0; kk < 2; ++kk) {
                const int row = wc * 64 + n * 16 + l15;
                bfr[n][kk] = *(const bf16x8*)(cur + 32768 + row * 128 + ((((kk << 2) | lq) ^ (row & 7)) << 4));
            }
#pragma unroll
        for (int m = 0; m < 4; ++m)
#pragma unroll
            for (int kk = 0; kk < 2; ++kk) {
                const int row = wr * 128 + m * 16 + l15;
                af[m][kk] = *(const bf16x8*)(cur + row * 128 + ((((kk << 2) | lq) ^ (row & 7)) << 4));
            }
        if (pre) {                                          // stage(t+1): 8 loads, fly all tile
            stageA1(nxt, t + 1, 0); stageA1(nxt, t + 1, 1);
            stageA1(nxt, t + 1, 2); stageA1(nxt, t + 1, 3);
            stageB1(nxt, t + 1, 0); stageB1(nxt, t + 1, 1);
            stageB1(nxt, t + 1, 2); stageB1(nxt, t + 1, 3);
        }
        __builtin_amdgcn_s_setprio(1);
#pragma unroll
        for (int m = 0; m < 4; ++m)
#pragma unroll
            for (int n = 0; n < 4; ++n)
#pragma unroll
                for (int kk = 0; kk < 2; ++kk)
                    acc[m][n] = __builtin_amdgcn_mfma_f32_16x16x32_bf16(af[m][kk], bfr[n][kk], acc[m][n], 0, 0, 0);
        __builtin_amdgcn_s_setprio(0);

        // second half: rows 64-127 of the wave's panel; same buffer, no sync needed
#pragma unroll
        for (int m = 0; m < 4; ++m)
#pragma unroll
            for (int kk = 0; kk < 2; ++kk) {
                const int row = wr * 128 + 64 + m * 16 + l15;
                af[m][kk] = *(const bf16x8*)(cur + row * 128 + ((((kk << 2) | lq) ^ (row & 7)) << 4));
            }
        __builtin_amdgcn_s_setprio(1);
#pragma unroll
        for (int m = 0; m < 4; ++m)
#pragma unroll
            for (int n = 0; n < 4; ++n)
#pragma unroll
                for (int kk = 0; kk < 2; ++kk)
                    acc[4 + m][n] = __builtin_amdgcn_mfma_f32_16x16x32_bf16(af[m][kk], bfr[n][kk], acc[4 + m][n], 0, 0, 0);
        __builtin_amdgcn_s_setprio(0);
    }

    // epilogue. C frag layout: row = lq*4 + r, col = l15
#pragma unroll
    for (int m = 0; m < 8; ++m) {
#pragma unroll
        for (int n = 0; n < 4; ++n) {
            const int colb = tn + wc * 64 + n * 16;   // wave-uniform 16-col group
            if (EPI == 2) {
#pragma unroll
                for (int r = 0; r < 4; ++r) {
                    const int row = tm + wr * 128 + m * 16 + lq * 4 + r;
                    outf[(size_t)row * N + colb + l15] = acc[m][n][r];
                }
            } else if (EPI == 1) {
#pragma unroll
                for (int r = 0; r < 4; ++r) {
                    const int row = tm + wr * 128 + m * 16 + lq * 4 + r;
                    const float v = acc[m][n][r];
                    outb[(size_t)row * N + colb + l15] = (bf16_t)(1.f / (1.f + __expf(-v)));
                }
            } else {
                const int head = colb / 384;
                const int jj = colb % 384;
                const int row0 = tm + wr * 128 + m * 16 + lq * 4;  // 4-aligned
                const int bidx = row0 >> 12;
                const int nn0 = row0 & 4095;
                const size_t bh = (size_t)(bidx * 16 + head);
                float sv[4];
#pragma unroll
                for (int r = 0; r < 4; ++r) {
                    const float v = acc[m][n][r];
                    sv[r] = v / (1.f + __expf(-v));    // silu
                }
                if (jj < 128) {
                    bf16_t* qp = qb + (bh * 4096 + nn0) * 128 + jj + l15;
#pragma unroll
                    for (int r = 0; r < 4; ++r) qp[(size_t)r * 128] = (bf16_t)sv[r];
                } else if (jj < 256) {
                    // row-major kb (for QK^T) + direct-transposed kT (for pass_ct)
                    bf16_t* kp = kb + (bh * 4096 + nn0) * 128 + (jj - 128) + l15;
#pragma unroll
                    for (int r = 0; r < 4; ++r) kp[(size_t)r * 128] = (bf16_t)sv[r];
                    bf16x4 pk;
#pragma unroll
                    for (int r = 0; r < 4; ++r) pk[r] = (bf16_t)sv[r];
                    *(bf16x4*)(kT + bh * 524288 + (size_t)(jj - 128 + l15) * 4096 + nn0) = pk;
                } else {
                    // v only needed feature-major: direct-transposed vT, no vb
                    bf16x4 pv;
#pragma unroll
                    for (int r = 0; r < 4; ++r) pv[r] = (bf16_t)sv[r];
                    *(bf16x4*)(vT + bh * 524288 + (size_t)(jj - 256 + l15) * 4096 + nn0) = pv;
                }
            }
        }
    }
}

// ---------------- per-block KV contribution with on-the-fly k-decay ----------------
// CT[e][d] = sum_m vT[e][m] * (kT[d][m] * exp(-s*(255-m)))
// decay via recurrence: f(t+1) = f(t) * e^s (f <= 1, monotone increasing)
__global__ __launch_bounds__(256)
void pass_ct(const bf16_t* __restrict__ vT, const bf16_t* __restrict__ kT,
             float* __restrict__ CT, const float* __restrict__ slopes) {
    const int idx = blockIdx.x, bh = idx >> 4, j = idx & 15;
    const float s = slopes[bh & 15];
    const float r_ = __expf(s);
    const int tid = threadIdx.x, w = tid >> 6, lane = tid & 63;
    const int l15 = lane & 15, lq = lane >> 4;
    const int we = (w & 1) * 64, wd = (w >> 1) * 64;
    const bf16_t* va = vT + (size_t)bh * 524288 + j * 256;
    const bf16_t* ka = kT + (size_t)bh * 524288 + j * 256;
    f32x4 acc[4][4] = {};
#pragma unroll
    for (int kk = 0; kk < 8; ++kk) {
        float fdec[8];
        fdec[0] = __expf(-s * (float)(255 - (kk * 32 + lq * 8)));
#pragma unroll
        for (int t = 1; t < 8; ++t) fdec[t] = fdec[t - 1] * r_;
        bf16x8 af[4], bfv[4];
#pragma unroll
        for (int et = 0; et < 4; ++et)
            af[et] = *(const bf16x8*)(va + (size_t)(we + et * 16 + l15) * 4096 + kk * 32 + lq * 8);
#pragma unroll
        for (int dt = 0; dt < 4; ++dt) {
            bf16x8 raw = *(const bf16x8*)(ka + (size_t)(wd + dt * 16 + l15) * 4096 + kk * 32 + lq * 8);
#pragma unroll
            for (int t = 0; t < 8; ++t) bfv[dt][t] = (bf16_t)((float)raw[t] * fdec[t]);
        }
#pragma unroll
        for (int et = 0; et < 4; ++et)
#pragma unroll
            for (int dt = 0; dt < 4; ++dt)
                acc[et][dt] = __builtin_amdgcn_mfma_f32_16x16x32_bf16(af[et], bfv[dt], acc[et][dt], 0, 0, 0);
    }
    float* out = CT + (size_t)idx * 16384;
#pragma unroll
    for (int et = 0; et < 4; ++et)
#pragma unroll
        for (int dt = 0; dt < 4; ++dt)
#pragma unroll
            for (int r = 0; r < 4; ++r)
                out[(size_t)(we + et * 16 + lq * 4 + r) * 128 + wd + dt * 16 + l15] = acc[et][dt][r];
}

// ---------------- sequential scan: states[j] = kv state before block j (bf16, [e][d]) ----------------
// one thread per (bh, elem): 32*16384 = 524288 scans; fully coalesced.
__global__ __launch_bounds__(256)
void scan_kv(const float* __restrict__ CT, bf16_t* __restrict__ states,
             const float* __restrict__ slopes) {
    const int gid = blockIdx.x * 256 + threadIdx.x;
    const int bh = gid >> 14, elem = gid & 16383;
    const float s = slopes[bh & 15];
    const float bd = __expf(-s * 256.f);
    const float* c = CT + (size_t)bh * 16 * 16384 + elem;
    bf16_t* st = states + (size_t)bh * 16 * 16384 + elem;
    float kv = 0.f;
#pragma unroll
    for (int j = 0; j < 16; ++j) {
        st[(size_t)j * 16384] = (bf16_t)kv;
        kv = bd * kv + c[(size_t)j * 16384];
    }
}

// ---------------- per-block output: o = (q*qdecay) @ stateT^T + (q@k^T . decay) @ v ----------------
// Balanced triangle: wave w owns 16-row groups {w, 15-w}; every wave does
// exactly 9 half-iters. Q hoisted; output written as bf16 (rmsnorm rounds
// to bf16 anyway; absmax validated in R15).
__global__ __launch_bounds__(512)
void pass_attn(const bf16_t* __restrict__ qb, const bf16_t* __restrict__ kb,
               const bf16_t* __restrict__ vT, const bf16_t* __restrict__ states,
               const float* __restrict__ slopes, bf16_t* __restrict__ outattn) {
    __shared__ bf16_t scratch[8][16][40];
    const int idx = blockIdx.x, bh = idx >> 4, j = idx & 15;
    const int b = bh >> 4, h = bh & 15;
    const int tid = threadIdx.x, w = tid >> 6, lane = tid & 63;
    const int l15 = lane & 15, lq = lane >> 4;
    const float s = slopes[h];
    f32x4 o[2][8] = {};    // [group][et]
    float rowf[4];         // exp(-s * local_row) ; local row within 16-group
#pragma unroll
    for (int r = 0; r < 4; ++r) rowf[r] = __expf(-s * (float)(lq * 4 + r));

    const size_t qrow = (size_t)bh * 4096 + j * 256;
    const bf16_t* qbase = qb + qrow * 128;
    const bf16_t* kbp = kb + qrow * 128;
    const bf16_t* vtp = vT + (size_t)bh * 524288 + (size_t)j * 256;

#pragma unroll
    for (int gi = 0; gi < 2; ++gi) {
        const int gg = gi ? (15 - w) : w;          // 16-row group index
        const bf16_t* qg = qbase + (size_t)(gg * 16) * 128;
        // hoist the wave's q fragments (loop-invariant across nc)
        bf16x8 qf[4];
#pragma unroll
        for (int kq = 0; kq < 4; ++kq)
            qf[kq] = *(const bf16x8*)(qg + (size_t)l15 * 128 + kq * 32 + lq * 8);
        const int ncmax = gg >> 1;                 // 32-col chunks needed
        for (int nc = 0; nc <= ncmax; ++nc) {
            f32x4 sacc[2] = {};
#pragma unroll
            for (int kq = 0; kq < 4; ++kq) {
                bf16x8 b0 = *(const bf16x8*)(kbp + (size_t)(nc * 32 + l15) * 128 + kq * 32 + lq * 8);
                bf16x8 b1 = *(const bf16x8*)(kbp + (size_t)(nc * 32 + 16 + l15) * 128 + kq * 32 + lq * 8);
                sacc[0] = __builtin_amdgcn_mfma_f32_16x16x32_bf16(qf[kq], b0, sacc[0], 0, 0, 0);
                sacc[1] = __builtin_amdgcn_mfma_f32_16x16x32_bf16(qf[kq], b1, sacc[1], 0, 0, 0);
            }
#pragma unroll
            for (int nt = 0; nt < 2; ++nt) {
                const float colf = __expf(s * (float)(nc * 32 + nt * 16 + l15 - gg * 16));
#pragma unroll
                for (int r = 0; r < 4; ++r) {
                    const int mloc = lq * 4 + r;                // local row in group
                    const int nglob = nc * 32 + nt * 16 + l15;  // global col
                    const float f = (gg * 16 + mloc >= nglob) ? rowf[r] * colf : 0.f;
                    scratch[w][mloc][nt * 16 + l15] = (bf16_t)(sacc[nt][r] * f);
                }
            }
            bf16x8 sa = *(const bf16x8*)&scratch[w][l15][lq * 8];
            __builtin_amdgcn_s_setprio(1);
#pragma unroll
            for (int et = 0; et < 8; ++et) {
                bf16x8 bv = *(const bf16x8*)(vtp + (size_t)(et * 16 + l15) * 4096 + nc * 32 + lq * 8);
                o[gi][et] = __builtin_amdgcn_mfma_f32_16x16x32_bf16(sa, bv, o[gi][et], 0, 0, 0);
            }
            __builtin_amdgcn_s_setprio(0);
        }
    }

    // inter-block part: o += (q * exp(-s*(row+1))) @ state
    float rq[2];
    rq[0] = __expf(-s * (float)(w * 16 + l15 + 1));
    rq[1] = __expf(-s * (float)((15 - w) * 16 + l15 + 1));
    const bf16_t* st = states + (size_t)idx * 16384;
#pragma unroll
    for (int kq = 0; kq < 4; ++kq) {
        bf16x8 aq[2];
#pragma unroll
        for (int gi = 0; gi < 2; ++gi) {
            const int gg = gi ? (15 - w) : w;
            bf16x8 raw = *(const bf16x8*)(qbase + (size_t)(gg * 16 + l15) * 128 + kq * 32 + lq * 8);
#pragma unroll
            for (int t = 0; t < 8; ++t) aq[gi][t] = (bf16_t)((float)raw[t] * rq[gi]);
        }
        __builtin_amdgcn_s_setprio(1);
#pragma unroll
        for (int et = 0; et < 8; ++et) {
            bf16x8 bs = *(const bf16x8*)(st + (size_t)(et * 16 + l15) * 128 + kq * 32 + lq * 8);
            o[0][et] = __builtin_amdgcn_mfma_f32_16x16x32_bf16(aq[0], bs, o[0][et], 0, 0, 0);
            o[1][et] = __builtin_amdgcn_mfma_f32_16x16x32_bf16(aq[1], bs, o[1][et], 0, 0, 0);
        }
        __builtin_amdgcn_s_setprio(0);
    }

    bf16_t* opb = outattn + ((size_t)b * 4096 + j * 256) * 2048 + h * 128;
#pragma unroll
    for (int gi = 0; gi < 2; ++gi) {
        const int gg = gi ? (15 - w) : w;
#pragma unroll
        for (int et = 0; et < 8; ++et)
#pragma unroll
            for (int r = 0; r < 4; ++r)
                opb[(size_t)(gg * 16 + lq * 4 + r) * 2048 + et * 16 + l15] = (bf16_t)o[gi][et][r];
    }
}

// ---------------- RMSNorm + sigmoid-gate fuse -> bf16 ----------------
__global__ __launch_bounds__(256)
void rmsnorm_gate(const bf16_t* __restrict__ attn, const bf16_t* __restrict__ gate_s,
                  const float* __restrict__ norm_w, bf16_t* __restrict__ gout) {
    const int row = blockIdx.x, tid = threadIdx.x;
    const bf16x8 a8 = *(const bf16x8*)(attn + (size_t)row * 2048 + tid * 8);
    float av[8];
#pragma unroll
    for (int i = 0; i < 8; ++i) av[i] = (float)a8[i];
    float ss = 0.f;
#pragma unroll
    for (int i = 0; i < 8; ++i) ss += av[i] * av[i];
#pragma unroll
    for (int off = 32; off; off >>= 1) ss += __shfl_xor(ss, off);
    __shared__ float red[4];
    if ((tid & 63) == 0) red[tid >> 6] = ss;
    __syncthreads();
    const float rr = rsqrtf((red[0] + red[1] + red[2] + red[3]) * (1.0f / 2048.f) + 1e-6f);
    const bf16x8 g = *(const bf16x8*)(gate_s + (size_t)row * 2048 + tid * 8);
    const float* nw = norm_w + tid * 8;
    bf16x8 res;
#pragma unroll
    for (int i = 0; i < 8; ++i) res[i] = (bf16_t)((float)g[i] * nw[i] * av[i] * rr);
    *(bf16x8*)(gout + (size_t)row * 2048 + tid * 8) = res;
}

// ---------------- launch ----------------
extern "C" void kernel_launch(void* const* d_in, const int* in_sizes, int n_in,
                              void* d_out, int out_size, void* d_ws, size_t ws_size,
                              hipStream_t stream) {
    (void)in_sizes; (void)n_in; (void)out_size;
    const float* x      = (const float*)d_in[0];
    const float* slopes = (const float*)d_in[1];
    const float* w_qkv  = (const float*)d_in[2];
    const float* w_gate = (const float*)d_in[3];
    const float* w_out  = (const float*)d_in[4];
    const float* norm_w = (const float*)d_in[5];
    float* out = (float*)d_out;
    char* ws = (char*)d_ws;

    size_t off = 0;
    auto alloc = [&](size_t bytes) { char* p = ws + off; off += (bytes + 255) & ~(size_t)255; return p; };
    bf16_t* xb     = (bf16_t*)alloc(8192ull * 2048 * 2);   // 33.6 MB
    bf16_t* wqkvb  = (bf16_t*)alloc(6144ull * 2048 * 2);   // 25.2 MB
    bf16_t* wgateb = (bf16_t*)alloc(2048ull * 2048 * 2);   //  8.4 MB
    bf16_t* woutb  = (bf16_t*)alloc(2048ull * 2048 * 2);   //  8.4 MB
    bf16_t* qb     = (bf16_t*)alloc(33554432);             // [bh][4096][128]
    bf16_t* kb     = (bf16_t*)alloc(33554432);             // [bh][4096][128]
    char*   ctbuf  = alloc(33554432);                      // CT scratch (32MB f32)
    bf16_t* vT     = (bf16_t*)alloc(33554432);             // [bh][128][4096]
    bf16_t* kT     = (bf16_t*)alloc(33554432);             // [bh][128][4096]
    if (ws_size < off) return;   // clean fail instead of OOB fault
    // aliases (producer runs strictly after last consumer of the aliased buffer):
    float*  CT     = (float*)ctbuf;    // pass_ct output (32 MB f32)
    bf16_t* gate_s = kT;               // gate GEMM output — kT dead after pass_ct
    bf16_t* states = (bf16_t*)wqkvb;   // scan output (16.8 MB) — wqkvb dead after gemm0
    bf16_t* attn_s = (bf16_t*)out;     // pass_attn bf16 scratch in d_out (read by rmsnorm
                                       // before gemm2 overwrites d_out with f32 result)
    bf16_t* gout   = qb;               // rmsnorm output — qb dead after pass_attn

    // 1. fused bf16 conversions (one launch)
    cvt4_kernel<<<2048, 256, 0, stream>>>(
        x,      xb,     8192 * 2048 / 4,
        w_qkv,  wqkvb,  6144 * 2048 / 4,
        w_gate, wgateb, 2048 * 2048 / 4,
        w_out,  woutb,  2048 * 2048 / 4);
    // 2. QKV projection + silu scatter; k/v written transposed in-epilogue
    gemm6<0><<<768, 512, 0, stream>>>(xb, wqkvb, 8192, 6144, 2048,
        nullptr, nullptr, qb, kb, kT, vT, slopes);
    // 3. per-block KV contributions (k-decay recurrence)
    pass_ct<<<512, 256, 0, stream>>>(vT, kT, CT, slopes);
    // 4. gate projection + sigmoid (writes over kT — dead)  (grid = 32*8 = 256)
    gemm6<1><<<256, 512, 0, stream>>>(xb, wgateb, 8192, 2048, 2048,
        nullptr, gate_s, nullptr, nullptr, nullptr, nullptr, nullptr);
    // 5. sequential KV scan (writes over wqkvb — dead); element-parallel
    scan_kv<<<2048, 256, 0, stream>>>(CT, states, slopes);
    // 6. attention block outputs -> bf16 scratch in d_out
    pass_attn<<<512, 512, 0, stream>>>(qb, kb, vT, states, slopes, attn_s);
    // 7. RMSNorm * norm_w * sigmoid(gate) -> bf16 (writes over qb — dead)
    rmsnorm_gate<<<8192, 256, 0, stream>>>(attn_s, gate_s, norm_w, gout);
    // 8. output projection -> d_out f32 (overwrites bf16 scratch after its last read)
    gemm6<2><<<256, 512, 0, stream>>>(gout, woutb, 8192, 2048, 2048,
        out, nullptr, nullptr, nullptr, nullptr, nullptr, nullptr);
}